// Round 1
// baseline (23727.231 us; speedup 1.0000x reference)
//
#include <hip/hip_runtime.h>
#include <cmath>

// ---------------------------------------------------------------------------
// 2-layer tanh RNN, B=64, T=512, D=H0=H1=1024.
// Persistent cooperative kernel, 4 WG groups self-timed via device-scope
// acquire/release counters (no grid barrier):
//   grp0 L0 : h0(t) = tanh(Wh0*h0(t-1) + U(t))            [K=1024]
//   grp1 L1a: p1(t) = Wh1*h1(t-1) + b1                    [K=1024]
//   grp2 L1b: h1(t) = tanh(W01*h0(t) + p1(t))             [K=1024]
//   grp3 U  : U(t)  = Wx*x(t) + b0  (no seq dep, runs ahead) [K=1024]
// Each group: 32 WGs x 32 cols, weight slice (32x1024 bf16 = 64 KB) persistent
// in LDS with XOR-16B swizzle (conflict-free ds_read_b128 B-fragments).
// MFMA: v_mfma_f32_16x16x32_bf16; A from global (L2-resident rings), fp32 acc.
// ---------------------------------------------------------------------------

typedef unsigned short u16;
typedef __bf16 bf16x8 __attribute__((ext_vector_type(8)));
typedef u16    u16x8  __attribute__((ext_vector_type(8)));
typedef u16    u16x4  __attribute__((ext_vector_type(4)));
typedef float  f32x4  __attribute__((ext_vector_type(4)));

constexpr int BB = 64;
constexpr int TT = 512;
constexpr int RING  = 16;   // h0/h1/p1 ring depth (steps)
constexpr int URING = 32;   // U ring depth
constexpr size_t SLOT = (size_t)64 * 1024;  // elements in one [B=64][1024] slab

// ws layout (bytes). Small stuff first; xb (bf16 x, time-major) last so we can
// fall back to direct fp32 x reads if ws_size is small.
constexpr size_t OFF_W0T = 16384;                                  // flags in [0,16K)
constexpr size_t OFF_W1T = OFF_W0T + (size_t)1024 * 2048 * 2;      // 4 MB each
constexpr size_t OFF_H0R = OFF_W1T + (size_t)1024 * 2048 * 2;
constexpr size_t OFF_H1R = OFF_H0R + (size_t)RING * SLOT * 2;
constexpr size_t OFF_UR  = OFF_H1R + (size_t)RING * SLOT * 2;
constexpr size_t OFF_P1R = OFF_UR  + (size_t)URING * SLOT * 4;
constexpr size_t OFF_XB  = OFF_P1R + (size_t)RING * SLOT * 4;      // ~25.2 MB up to here
constexpr size_t WS_FULL = OFF_XB  + (size_t)TT * SLOT * 2;        // ~92.3 MB total

__device__ inline u16 f2bf(float f) {
  return __builtin_bit_cast(u16, (__bf16)f);   // RNE f32->bf16
}

// ---------------------------------------------------------------- prep kernels
__global__ void zero_flags(unsigned* ws) {
  for (int i = threadIdx.x; i < 4096; i += 256) ws[i] = 0;  // 16 KB flag region
}

// W [2048][1024] fp32 row-major -> Wt [1024 n][2048 k] bf16 (transpose+convert)
__global__ void transpose_w(const float* __restrict__ W0,
                            const float* __restrict__ W1,
                            u16* __restrict__ wt_base) {
  __shared__ float tile[64][65];
  int bi  = blockIdx.x;
  int mat = bi >> 9;
  int t   = bi & 511;
  int tk = t & 31, tn = t >> 5;
  const float* W = mat ? W1 : W0;
  u16* Wt = wt_base + (size_t)mat * 1024 * 2048;
  int K0 = tk * 64, N0 = tn * 64;
  int tid = threadIdx.x;
  {
    int c4 = (tid & 15) * 4;
    int r  = tid >> 4;
    for (int i = 0; i < 4; ++i) {
      int kl = r + i * 16;
      float4 v = *(const float4*)(W + (size_t)(K0 + kl) * 1024 + N0 + c4);
      tile[kl][c4 + 0] = v.x; tile[kl][c4 + 1] = v.y;
      tile[kl][c4 + 2] = v.z; tile[kl][c4 + 3] = v.w;
    }
  }
  __syncthreads();
  {
    int nl = tid >> 3;
    int kc = (tid & 7) * 8;
    for (int pass = 0; pass < 2; ++pass) {
      int n = nl + pass * 32;
      u16x8 o;
      #pragma unroll
      for (int z = 0; z < 8; ++z) o[z] = f2bf(tile[kc + z][n]);
      *(u16x8*)(Wt + (size_t)(N0 + n) * 2048 + K0 + kc) = o;
    }
  }
}

// x [B][T][1024] fp32 -> xb [T][B][1024] bf16 (time-major)
__global__ void xconv(const float* __restrict__ x, u16* __restrict__ xb) {
  int bi = blockIdx.x;               // 32768 = B*T
  int b = bi >> 9, t = bi & 511;
  const float* src = x + ((size_t)b * TT + t) * 1024;
  u16* dst = xb + ((size_t)t * BB + b) * 1024;
  int i = threadIdx.x * 4;
  float4 v = *(const float4*)(src + i);
  u16x4 o; o[0] = f2bf(v.x); o[1] = f2bf(v.y); o[2] = f2bf(v.z); o[3] = f2bf(v.w);
  *(u16x4*)(dst + i) = o;
}

// ------------------------------------------------------------------- sync ops
__device__ inline void wait_ge(const unsigned* p, unsigned tgt) {
  if (threadIdx.x == 0) {
    while (__hip_atomic_load(p, __ATOMIC_ACQUIRE, __HIP_MEMORY_SCOPE_AGENT) < tgt)
      __builtin_amdgcn_s_sleep(2);
  }
  __syncthreads();
}

__device__ inline void signal(unsigned* p) {
  __threadfence();            // make our stores agent-visible
  __syncthreads();
  if (threadIdx.x == 0)
    __hip_atomic_fetch_add(p, 1u, __ATOMIC_RELEASE, __HIP_MEMORY_SCOPE_AGENT);
}

// ------------------------------------------------------------- main persistent
__global__ void __launch_bounds__(256, 1)
rnn_seq(const float* __restrict__ x, const float* __restrict__ b0v,
        const float* __restrict__ b1v, float* __restrict__ out,
        unsigned char* __restrict__ ws, int use_xb) {
  extern __shared__ u16 lds[];   // 32 cols x 1024 k bf16, swizzled = 64 KB
  unsigned* cnt_h0 = (unsigned*)(ws);
  unsigned* cnt_p1 = (unsigned*)(ws + 2048);
  unsigned* cnt_h1 = (unsigned*)(ws + 4096);
  unsigned* cnt_u  = (unsigned*)(ws + 6144);
  u16*   W0t = (u16*)(ws + OFF_W0T);
  u16*   W1t = (u16*)(ws + OFF_W1T);
  u16*   h0r = (u16*)(ws + OFF_H0R);
  u16*   h1r = (u16*)(ws + OFF_H1R);
  float* Ur  = (float*)(ws + OFF_UR);
  float* p1r = (float*)(ws + OFF_P1R);
  u16*   xb  = (u16*)(ws + OFF_XB);

  int wg = blockIdx.x, tid = threadIdx.x;
  int grp = wg >> 5, j = wg & 31;
  int n0 = j * 32;                       // this WG's output-column base
  int lane = tid & 63, wave = tid >> 6;
  int n15 = lane & 15, q = lane >> 4;
  int r0 = wave * 16;                    // this wave's 16 batch rows

  // ---- fill persistent LDS weight slice: Wt[n0+n][kbase+k], swizzled [n][k]
  const u16* Wt  = (grp == 1 || grp == 2) ? W1t : W0t;
  int kbase      = (grp == 0 || grp == 1) ? 0 : 1024;
  for (int idx = tid; idx < 32 * 128; idx += 256) {
    int n = idx >> 7, g = idx & 127;     // g = 16B group along k
    u16x8 v = *(const u16x8*)(Wt + (size_t)(n0 + n) * 2048 + kbase + g * 8);
    *(u16x8*)(lds + n * 1024 + ((g ^ (n & 15)) * 8)) = v;
  }
  __syncthreads();

  const size_t aoff = (size_t)(r0 + n15) * 1024 + q * 8;  // bf16 A lane offset

  // C = A[64x1024] * Wslice[1024x32]; wave: 16 rows x 32 cols (2 MFMA tiles)
  auto mm = [&](const u16* Abase, f32x4& acc0, f32x4& acc1) {
    const u16* ap = Abase + aoff;
    const u16* bp = lds + n15 * 1024;
    #pragma unroll
    for (int ks = 0; ks < 32; ++ks) {
      bf16x8 a  = __builtin_bit_cast(bf16x8, *(const u16x8*)(ap + ks * 32));
      int g = (4 * ks + q) ^ n15;        // swizzled 16B group
      bf16x8 b0 = __builtin_bit_cast(bf16x8, *(const u16x8*)(bp + g * 8));
      bf16x8 b1 = __builtin_bit_cast(bf16x8, *(const u16x8*)(bp + 16 * 1024 + g * 8));
      acc0 = __builtin_amdgcn_mfma_f32_16x16x32_bf16(a, b0, acc0, 0, 0, 0);
      acc1 = __builtin_amdgcn_mfma_f32_16x16x32_bf16(a, b1, acc1, 0, 0, 0);
    }
  };
  // same, A read as fp32 with inline cvt (fallback when xb doesn't fit in ws)
  auto mmf = [&](const float* Ap, f32x4& acc0, f32x4& acc1) {
    const u16* bp = lds + n15 * 1024;
    #pragma unroll
    for (int ks = 0; ks < 32; ++ks) {
      float4 v0 = *(const float4*)(Ap + ks * 32);
      float4 v1 = *(const float4*)(Ap + ks * 32 + 4);
      bf16x8 a;
      a[0]=(__bf16)v0.x; a[1]=(__bf16)v0.y; a[2]=(__bf16)v0.z; a[3]=(__bf16)v0.w;
      a[4]=(__bf16)v1.x; a[5]=(__bf16)v1.y; a[6]=(__bf16)v1.z; a[7]=(__bf16)v1.w;
      int g = (4 * ks + q) ^ n15;
      bf16x8 b0 = __builtin_bit_cast(bf16x8, *(const u16x8*)(bp + g * 8));
      bf16x8 b1 = __builtin_bit_cast(bf16x8, *(const u16x8*)(bp + 16 * 1024 + g * 8));
      acc0 = __builtin_amdgcn_mfma_f32_16x16x32_bf16(a, b0, acc0, 0, 0, 0);
      acc1 = __builtin_amdgcn_mfma_f32_16x16x32_bf16(a, b1, acc1, 0, 0, 0);
    }
  };
  // C/D layout (verified m89): col = lane&15, row = (lane>>4)*4 + i
  auto epi = [&](const f32x4& acc0, const f32x4& acc1, auto&& fn) {
    #pragma unroll
    for (int tile = 0; tile < 2; ++tile) {
      const f32x4& a = tile ? acc1 : acc0;
      int nn = n0 + n15 + tile * 16;
      #pragma unroll
      for (int i = 0; i < 4; ++i) {
        int b = r0 + q * 4 + i;
        fn(b, nn, a[i]);
      }
    }
  };

  const size_t FIN = (size_t)BB * TT * 1024;   // final-state offset in d_out

  if (grp == 0) {            // ---- L0: h0(t) = tanh(Wh0*h0(t-1) + U(t))
    for (int t = 0; t < TT; ++t) {
      if (t >= RING) wait_ge(&cnt_h1[t - RING], 32);  // h0 ring reuse gate
      f32x4 acc0 = {0.f, 0.f, 0.f, 0.f}, acc1 = acc0;
      if (t > 0) {
        wait_ge(&cnt_h0[t - 1], 32);
        mm(h0r + (size_t)((t - 1) & (RING - 1)) * SLOT, acc0, acc1);
      }
      wait_ge(&cnt_u[t], 32);
      const float* U = Ur + (size_t)(t & (URING - 1)) * SLOT;
      u16* H = h0r + (size_t)(t & (RING - 1)) * SLOT;
      epi(acc0, acc1, [&](int b, int nn, float a) {
        float h = tanhf(a + U[b * 1024 + nn]);
        H[b * 1024 + nn] = f2bf(h);
        if (t == TT - 1) out[FIN + (size_t)b * 2048 + nn] = h;
      });
      signal(&cnt_h0[t]);
    }
  } else if (grp == 1) {     // ---- L1a: p1(t) = Wh1*h1(t-1) + b1
    for (int t = 0; t < TT; ++t) {
      if (t >= RING) wait_ge(&cnt_h1[t - RING], 32);  // p1 ring reuse gate
      float* P = p1r + (size_t)(t & (RING - 1)) * SLOT;
      if (t == 0) {
        for (int idx = tid; idx < 64 * 32; idx += 256) {
          int b = idx >> 5, c = idx & 31;
          P[b * 1024 + n0 + c] = b1v[n0 + c];
        }
      } else {
        wait_ge(&cnt_h1[t - 1], 32);
        f32x4 acc0 = {0.f, 0.f, 0.f, 0.f}, acc1 = acc0;
        mm(h1r + (size_t)((t - 1) & (RING - 1)) * SLOT, acc0, acc1);
        epi(acc0, acc1, [&](int b, int nn, float a) {
          P[b * 1024 + nn] = a + b1v[nn];
        });
      }
      signal(&cnt_p1[t]);
    }
  } else if (grp == 2) {     // ---- L1b: h1(t) = tanh(W01*h0(t) + p1(t))
    for (int t = 0; t < TT; ++t) {
      wait_ge(&cnt_h0[t], 32);
      wait_ge(&cnt_p1[t], 32);
      f32x4 acc0 = {0.f, 0.f, 0.f, 0.f}, acc1 = acc0;
      mm(h0r + (size_t)(t & (RING - 1)) * SLOT, acc0, acc1);
      const float* P = p1r + (size_t)(t & (RING - 1)) * SLOT;
      u16* H = h1r + (size_t)(t & (RING - 1)) * SLOT;
      epi(acc0, acc1, [&](int b, int nn, float a) {
        float h = tanhf(a + P[b * 1024 + nn]);
        H[b * 1024 + nn] = f2bf(h);
        out[((size_t)b * TT + t) * 1024 + nn] = h;
        if (t == TT - 1) out[FIN + (size_t)b * 2048 + 1024 + nn] = h;
      });
      signal(&cnt_h1[t]);
    }
  } else {                   // ---- U: U(t) = Wx*x(t) + b0 (runs ahead)
    for (int t = 0; t < TT; ++t) {
      if (t >= URING) wait_ge(&cnt_h0[t - URING], 32);  // U ring reuse gate
      f32x4 acc0 = {0.f, 0.f, 0.f, 0.f}, acc1 = acc0;
      if (use_xb) {
        mm(xb + (size_t)t * SLOT, acc0, acc1);
      } else {
        const float* Ap = x + ((size_t)(r0 + n15) * TT + t) * 1024 + q * 8;
        mmf(Ap, acc0, acc1);
      }
      float* U = Ur + (size_t)(t & (URING - 1)) * SLOT;
      epi(acc0, acc1, [&](int b, int nn, float a) {
        U[b * 1024 + nn] = a + b0v[nn];
      });
      signal(&cnt_u[t]);
    }
  }
}

// ------------------------------------------------------------------ host side
extern "C" void kernel_launch(void* const* d_in, const int* in_sizes, int n_in,
                              void* d_out, int out_size, void* d_ws, size_t ws_size,
                              hipStream_t stream) {
  const float* x  = (const float*)d_in[0];
  const float* W0 = (const float*)d_in[1];
  const float* b0 = (const float*)d_in[2];
  const float* W1 = (const float*)d_in[3];
  const float* b1 = (const float*)d_in[4];
  float* out = (float*)d_out;
  unsigned char* ws = (unsigned char*)d_ws;
  int use_xb = (ws_size >= WS_FULL) ? 1 : 0;   // fall back if ws too small

  zero_flags<<<1, 256, 0, stream>>>((unsigned*)ws);
  transpose_w<<<1024, 256, 0, stream>>>(W0, W1, (u16*)(ws + OFF_W0T));
  if (use_xb) xconv<<<32768, 256, 0, stream>>>(x, (u16*)(ws + OFF_XB));

  void* args[6];
  args[0] = (void*)&x;   args[1] = (void*)&b0;  args[2] = (void*)&b1;
  args[3] = (void*)&out; args[4] = (void*)&ws;  args[5] = (void*)&use_xb;
  // cooperative launch: guarantees all 128 WGs co-resident (1 per CU, 64 KB LDS)
  hipLaunchCooperativeKernel((void*)rnn_seq, dim3(128), dim3(256), args,
                             65536, stream);
}

// Round 2
// 6164.148 us; speedup vs baseline: 3.8492x; 3.8492x over previous
//
#include <hip/hip_runtime.h>
#include <cmath>

// ---------------------------------------------------------------------------
// 2-layer tanh RNN, B=64, T=512, D=H0=H1=1024. Persistent cooperative kernel.
// 3 WG groups, self-timed via per-producer flags (release store / relaxed poll
// + single acquire fence -- NO per-poll cache maintenance, NO RMW fan-in):
//   G0 (32 WG): h0(t) = tanh(Wh0*h0(t-1) + U(t))                [K=1024]
//   G1 (32 WG): h1(t) = tanh(W1*[h1(t-1); h0(t)] + b1)          [K=2048]
//   G2 (32 WG): U(t)  = Wx*x(t) + b0   (no seq dep, runs ahead) [K=1024]
// Weights persistent in LDS (G1: 128 KB, two 64 KB halves), XOR-16B swizzle
// (bank-conflict-free, verified round 1). MFMA 16x16x32 bf16, fp32 acc.
// Critical loops: h0(t-1)->G0->h0(t)  and  h1(t-1)->G1->h1(t): 1 handoff each.
// ---------------------------------------------------------------------------

typedef unsigned short u16;
typedef __bf16 bf16x8 __attribute__((ext_vector_type(8)));
typedef u16    u16x8  __attribute__((ext_vector_type(8)));
typedef u16    u16x4  __attribute__((ext_vector_type(4)));
typedef float  f32x4  __attribute__((ext_vector_type(4)));

constexpr int BB = 64;
constexpr int TT = 512;
constexpr int RING  = 16;   // h0/h1 ring depth (steps)
constexpr int URING = 32;   // U ring depth
constexpr size_t SLOT = (size_t)64 * 1024;  // elements in one [B=64][1024] slab

// ws layout (bytes). flags: 3 channels x 512 steps x 32 producer-words.
constexpr size_t OFF_FLAGS = 0;                                    // 196608 B
constexpr size_t OFF_W0T = 262144;
constexpr size_t OFF_W1T = OFF_W0T + (size_t)1024 * 2048 * 2;      // 4 MB each
constexpr size_t OFF_H0R = OFF_W1T + (size_t)1024 * 2048 * 2;
constexpr size_t OFF_H1R = OFF_H0R + (size_t)RING * SLOT * 2;
constexpr size_t OFF_UR  = OFF_H1R + (size_t)RING * SLOT * 2;
constexpr size_t OFF_XB  = OFF_UR  + (size_t)URING * SLOT * 4;
constexpr size_t WS_FULL = OFF_XB  + (size_t)TT * SLOT * 2;        // ~84.3 MB

__device__ inline u16 f2bf(float f) {
  return __builtin_bit_cast(u16, (__bf16)f);   // RNE f32->bf16
}

// fast tanh: (e^{2x}-1)/(e^{2x}+1), clamp so exp never overflows. abs err
// ~1e-6 -- negligible vs the 2e-2 bf16 threshold (round-1 absmax was 0.011).
__device__ inline float fast_tanh(float x) {
  x = fminf(15.f, fmaxf(-15.f, x));
  float e = __expf(2.f * x);
  return (e - 1.f) * __builtin_amdgcn_rcpf(e + 1.f);
}

// ---------------------------------------------------------------- prep kernels
__global__ void zero_flags(unsigned* f) {
  int i = blockIdx.x * 256 + threadIdx.x;
  if (i < 3 * 512 * 32) f[i] = 0;
}

// W [2048][1024] fp32 row-major -> Wt [1024 n][2048 k] bf16 (transpose+convert)
__global__ void transpose_w(const float* __restrict__ W0,
                            const float* __restrict__ W1,
                            u16* __restrict__ wt_base) {
  __shared__ float tile[64][65];
  int bi  = blockIdx.x;
  int mat = bi >> 9;
  int t   = bi & 511;
  int tk = t & 31, tn = t >> 5;
  const float* W = mat ? W1 : W0;
  u16* Wt = wt_base + (size_t)mat * 1024 * 2048;
  int K0 = tk * 64, N0 = tn * 64;
  int tid = threadIdx.x;
  {
    int c4 = (tid & 15) * 4;
    int r  = tid >> 4;
    for (int i = 0; i < 4; ++i) {
      int kl = r + i * 16;
      float4 v = *(const float4*)(W + (size_t)(K0 + kl) * 1024 + N0 + c4);
      tile[kl][c4 + 0] = v.x; tile[kl][c4 + 1] = v.y;
      tile[kl][c4 + 2] = v.z; tile[kl][c4 + 3] = v.w;
    }
  }
  __syncthreads();
  {
    int nl = tid >> 3;
    int kc = (tid & 7) * 8;
    for (int pass = 0; pass < 2; ++pass) {
      int n = nl + pass * 32;
      u16x8 o;
      #pragma unroll
      for (int z = 0; z < 8; ++z) o[z] = f2bf(tile[kc + z][n]);
      *(u16x8*)(Wt + (size_t)(N0 + n) * 2048 + K0 + kc) = o;
    }
  }
}

// x [B][T][1024] fp32 -> xb [T][B][1024] bf16 (time-major)
__global__ void xconv(const float* __restrict__ x, u16* __restrict__ xb) {
  int bi = blockIdx.x;               // 32768 = B*T
  int b = bi >> 9, t = bi & 511;
  const float* src = x + ((size_t)b * TT + t) * 1024;
  u16* dst = xb + ((size_t)t * BB + b) * 1024;
  int i = threadIdx.x * 4;
  float4 v = *(const float4*)(src + i);
  u16x4 o; o[0] = f2bf(v.x); o[1] = f2bf(v.y); o[2] = f2bf(v.z); o[3] = f2bf(v.w);
  *(u16x4*)(dst + i) = o;
}

// ------------------------------------------------------------------- sync ops
// Relaxed poll: NO cache-maintenance per iteration (round-1 killer).
__device__ inline void poll1(const unsigned* p) {
  while (__hip_atomic_load(p, __ATOMIC_RELAXED, __HIP_MEMORY_SCOPE_AGENT) == 0u)
    __builtin_amdgcn_s_sleep(4);
}

// ------------------------------------------------------------- main persistent
__global__ void __launch_bounds__(256, 1)
rnn_seq(const float* __restrict__ x, const float* __restrict__ b0v,
        const float* __restrict__ b1v, float* __restrict__ out,
        unsigned char* __restrict__ ws, int use_xb) {
  extern __shared__ u16 lds[];   // G1: 2 halves x (32 cols x 1024 k) = 128 KB
  unsigned* fl_h0 = (unsigned*)(ws + OFF_FLAGS);            // [512][32]
  unsigned* fl_h1 = fl_h0 + 512 * 32;
  unsigned* fl_u  = fl_h0 + 2 * 512 * 32;
  u16*   W0t = (u16*)(ws + OFF_W0T);
  u16*   W1t = (u16*)(ws + OFF_W1T);
  u16*   h0r = (u16*)(ws + OFF_H0R);
  u16*   h1r = (u16*)(ws + OFF_H1R);
  float* Ur  = (float*)(ws + OFF_UR);
  u16*   xb  = (u16*)(ws + OFF_XB);

  int wg = blockIdx.x, tid = threadIdx.x;
  int grp = wg >> 5, j = wg & 31;        // 0=L0, 1=L1(full), 2=U
  int n0 = j * 32;                       // this WG's output-column base
  int lane = tid & 63, wave = tid >> 6;
  int n15 = lane & 15, q = lane >> 4;
  int r0 = wave * 16;                    // this wave's 16 batch rows

  // ---- fill persistent LDS weight slice(s), XOR-16B swizzled [n][k]
  {
    const u16* Wt = (grp == 1) ? W1t : W0t;
    int nh = (grp == 1) ? 2 : 1;
    for (int h = 0; h < nh; ++h) {
      int kb = (grp == 1) ? h * 1024 : (grp == 2 ? 1024 : 0);
      for (int idx = tid; idx < 32 * 128; idx += 256) {
        int n = idx >> 7, g = idx & 127;     // g = 16B group along k
        u16x8 v = *(const u16x8*)(Wt + (size_t)(n0 + n) * 2048 + kb + g * 8);
        *(u16x8*)(lds + h * 32768 + n * 1024 + ((g ^ (n & 15)) * 8)) = v;
      }
    }
  }
  __syncthreads();

  const size_t aoff = (size_t)(r0 + n15) * 1024 + q * 8;  // bf16 A lane offset

  // C = A[64x1024] * Wslice[1024x32]; wave: 16 rows x 32 cols (2 MFMA tiles)
  auto mm = [&](const u16* Abase, const u16* bbase, f32x4& acc0, f32x4& acc1) {
    const u16* ap = Abase + aoff;
    const u16* bp = bbase + n15 * 1024;
    #pragma unroll
    for (int ks = 0; ks < 32; ++ks) {
      bf16x8 a  = __builtin_bit_cast(bf16x8, *(const u16x8*)(ap + ks * 32));
      int g = (4 * ks + q) ^ n15;        // swizzled 16B group
      bf16x8 b0 = __builtin_bit_cast(bf16x8, *(const u16x8*)(bp + g * 8));
      bf16x8 b1 = __builtin_bit_cast(bf16x8, *(const u16x8*)(bp + 16 * 1024 + g * 8));
      acc0 = __builtin_amdgcn_mfma_f32_16x16x32_bf16(a, b0, acc0, 0, 0, 0);
      acc1 = __builtin_amdgcn_mfma_f32_16x16x32_bf16(a, b1, acc1, 0, 0, 0);
    }
  };
  // same, A read as fp32 with inline cvt (fallback when xb doesn't fit in ws)
  auto mmf = [&](const float* Ap, f32x4& acc0, f32x4& acc1) {
    const u16* bp = lds + n15 * 1024;
    #pragma unroll
    for (int ks = 0; ks < 32; ++ks) {
      float4 v0 = *(const float4*)(Ap + ks * 32);
      float4 v1 = *(const float4*)(Ap + ks * 32 + 4);
      bf16x8 a;
      a[0]=(__bf16)v0.x; a[1]=(__bf16)v0.y; a[2]=(__bf16)v0.z; a[3]=(__bf16)v0.w;
      a[4]=(__bf16)v1.x; a[5]=(__bf16)v1.y; a[6]=(__bf16)v1.z; a[7]=(__bf16)v1.w;
      int g = (4 * ks + q) ^ n15;
      bf16x8 b0 = __builtin_bit_cast(bf16x8, *(const u16x8*)(bp + g * 8));
      bf16x8 b1 = __builtin_bit_cast(bf16x8, *(const u16x8*)(bp + 16 * 1024 + g * 8));
      acc0 = __builtin_amdgcn_mfma_f32_16x16x32_bf16(a, b0, acc0, 0, 0, 0);
      acc1 = __builtin_amdgcn_mfma_f32_16x16x32_bf16(a, b1, acc1, 0, 0, 0);
    }
  };
  // C/D layout (verified round 1): col = lane&15 (+16/tile), row = q*4 + i
  auto epi = [&](const f32x4& acc0, const f32x4& acc1, auto&& fn) {
    #pragma unroll
    for (int tile = 0; tile < 2; ++tile) {
      const f32x4& a = tile ? acc1 : acc0;
      int nn = n0 + n15 + tile * 16;
      #pragma unroll
      for (int i = 0; i < 4; ++i) {
        int b = r0 + q * 4 + i;
        fn(b, nn, a[i]);
      }
    }
  };

  const size_t FIN = (size_t)BB * TT * 1024;   // final-state offset in d_out

  if (grp == 0) {            // ---- G0: h0(t) = tanh(Wh0*h0(t-1) + U(t))
    for (int t = 0; t < TT; ++t) {
      // one combined wait: reads gated in wave 0, WAR ring-gate in wave 1
      if (tid < 32)       { if (t > 0)     poll1(&fl_h0[(t-1)*32 + tid]); }
      else if (tid < 64)  {                poll1(&fl_u [t*32 + (tid-32)]); }
      else if (tid < 96)  { if (t >= RING) poll1(&fl_h1[(t-RING)*32 + (tid-64)]); }
      if (tid < 64) __builtin_amdgcn_fence(__ATOMIC_ACQUIRE, "agent"); // 1 inv/WG
      __syncthreads();
      f32x4 acc0 = {0.f, 0.f, 0.f, 0.f}, acc1 = acc0;
      if (t > 0) mm(h0r + (size_t)((t-1) & (RING-1)) * SLOT, lds, acc0, acc1);
      const float* U = Ur + (size_t)(t & (URING-1)) * SLOT;
      u16* H = h0r + (size_t)(t & (RING-1)) * SLOT;
      epi(acc0, acc1, [&](int b, int nn, float a) {
        float h = fast_tanh(a + U[b * 1024 + nn]);
        H[b * 1024 + nn] = f2bf(h);
        if (t == TT-1) __builtin_nontemporal_store(h, &out[FIN + (size_t)b*2048 + nn]);
      });
      __syncthreads();       // peers' stores drained (vmcnt0) before release
      if (tid == 0)
        __hip_atomic_store(&fl_h0[t*32 + j], 1u, __ATOMIC_RELEASE, __HIP_MEMORY_SCOPE_AGENT);
    }
  } else if (grp == 1) {     // ---- G1: h1(t) = tanh(W1*[h1(t-1); h0(t)] + b1)
    for (int t = 0; t < TT; ++t) {
      if (tid < 32)      {              poll1(&fl_h0[t*32 + tid]); }
      else if (tid < 64) { if (t > 0)   poll1(&fl_h1[(t-1)*32 + (tid-32)]); }
      if (tid < 64) __builtin_amdgcn_fence(__ATOMIC_ACQUIRE, "agent");
      __syncthreads();
      f32x4 acc0 = {0.f, 0.f, 0.f, 0.f}, acc1 = acc0;
      if (t > 0) mm(h1r + (size_t)((t-1) & (RING-1)) * SLOT, lds,         acc0, acc1);
      mm(h0r + (size_t)(t & (RING-1)) * SLOT,                lds + 32768, acc0, acc1);
      u16* H = h1r + (size_t)(t & (RING-1)) * SLOT;
      epi(acc0, acc1, [&](int b, int nn, float a) {
        float h = fast_tanh(a + b1v[nn]);
        H[b * 1024 + nn] = f2bf(h);
        __builtin_nontemporal_store(h, &out[((size_t)b * TT + t) * 1024 + nn]);
        if (t == TT-1) __builtin_nontemporal_store(h, &out[FIN + (size_t)b*2048 + 1024 + nn]);
      });
      __syncthreads();
      if (tid == 0)
        __hip_atomic_store(&fl_h1[t*32 + j], 1u, __ATOMIC_RELEASE, __HIP_MEMORY_SCOPE_AGENT);
    }
  } else {                   // ---- G2: U(t) = Wx*x(t) + b0 (runs ahead)
    for (int t = 0; t < TT; ++t) {
      if (t >= URING) {      // pure WAR gate: no acquire fence needed
        if (tid < 32) poll1(&fl_h0[(t-URING)*32 + tid]);
        __syncthreads();
      }
      f32x4 acc0 = {0.f, 0.f, 0.f, 0.f}, acc1 = acc0;
      if (use_xb) {
        mm(xb + (size_t)t * SLOT, lds, acc0, acc1);
      } else {
        const float* Ap = x + ((size_t)(r0 + n15) * TT + t) * 1024 + q * 8;
        mmf(Ap, acc0, acc1);
      }
      float* U = Ur + (size_t)(t & (URING-1)) * SLOT;
      epi(acc0, acc1, [&](int b, int nn, float a) {
        U[b * 1024 + nn] = a + b0v[nn];
      });
      __syncthreads();
      if (tid == 0)
        __hip_atomic_store(&fl_u[t*32 + j], 1u, __ATOMIC_RELEASE, __HIP_MEMORY_SCOPE_AGENT);
    }
  }
}

// ------------------------------------------------------------------ host side
extern "C" void kernel_launch(void* const* d_in, const int* in_sizes, int n_in,
                              void* d_out, int out_size, void* d_ws, size_t ws_size,
                              hipStream_t stream) {
  const float* x  = (const float*)d_in[0];
  const float* W0 = (const float*)d_in[1];
  const float* b0 = (const float*)d_in[2];
  const float* W1 = (const float*)d_in[3];
  const float* b1 = (const float*)d_in[4];
  float* out = (float*)d_out;
  unsigned char* ws = (unsigned char*)d_ws;
  int use_xb = (ws_size >= WS_FULL) ? 1 : 0;   // fall back if ws too small

  zero_flags<<<(3*512*32 + 255)/256, 256, 0, stream>>>((unsigned*)ws);
  transpose_w<<<1024, 256, 0, stream>>>(W0, W1, (u16*)(ws + OFF_W0T));
  if (use_xb) xconv<<<32768, 256, 0, stream>>>(x, (u16*)(ws + OFF_XB));

  // G1 needs 128 KB dynamic LDS; opt-in in case runtime caps at 64 KB
  // (capture-safe: attribute set is not a stream op). Ignore failure --
  // gfx950 has 160 KB/CU and ROCm generally allows it directly.
  (void)hipFuncSetAttribute((const void*)rnn_seq,
                            hipFuncAttributeMaxDynamicSharedMemorySize, 131072);

  void* args[6];
  args[0] = (void*)&x;   args[1] = (void*)&b0;  args[2] = (void*)&b1;
  args[3] = (void*)&out; args[4] = (void*)&ws;  args[5] = (void*)&use_xb;
  // cooperative launch: 96 WGs co-resident (1 per CU at 128 KB LDS)
  hipLaunchCooperativeKernel((void*)rnn_seq, dim3(96), dim3(256), args,
                             131072, stream);
}

// Round 3
// 5388.929 us; speedup vs baseline: 4.4030x; 1.1439x over previous
//
#include <hip/hip_runtime.h>
#include <cmath>

// ---------------------------------------------------------------------------
// 2-layer tanh RNN, B=64, T=512, D=H0=H1=1024. Persistent cooperative kernel.
// Round-3 change: ZERO cache-maintenance sync. All cross-WG data/flag stores
// are relaxed SYSTEM-scope (sc0 sc1: write-through to coherent point, no
// buffer_wbl2); flag polls are relaxed SYSTEM loads (no buffer_inv).
// Producer ordering: __syncthreads() drains vmcnt(0) before tid0's flag store.
// Consumer freshness: PLAIN mode = no-reuse rings (512 slots, cached loads);
// COH mode = small rings + sc1 (system-scope atomic) data loads.
//   G0 (32 WG): h0(t) = tanh(Wh0*h0(t-1) + U(t))                [K=1024]
//   G1 (32 WG): h1(t) = tanh(W1*[h1(t-1); h0(t)] + b1)          [K=2048]
//   G2 (32 WG): U(t)  = Wx*x(t) + b0   (free-runs ahead)        [K=1024]
// Weights persistent in LDS, XOR-16B swizzle (0 bank conflicts, verified).
// ---------------------------------------------------------------------------

typedef unsigned short u16;
typedef unsigned long long u64;
typedef __bf16 bf16x8 __attribute__((ext_vector_type(8)));
typedef u16    u16x8  __attribute__((ext_vector_type(8)));
typedef u16    u16x4  __attribute__((ext_vector_type(4)));
typedef float  f32x4  __attribute__((ext_vector_type(4)));

constexpr int BB = 64;
constexpr int TT = 512;
constexpr size_t SLOT   = (size_t)64 * 1024;   // elements per [64][1024] slab
constexpr size_t SLAB_B = SLOT * 2;            // 128 KB bf16 slab

// ws layout: [flags 256KB][W0t 4MB][W1t 4MB][h0r][h1r][Ur][xb]
constexpr size_t OFF_W0T = 262144;
constexpr size_t OFF_W1T = OFF_W0T + (size_t)1024 * 2048 * 2;
constexpr size_t OFF_R   = OFF_W1T + (size_t)1024 * 2048 * 2;   // 8650752

__device__ inline u16 f2bf(float f) {
  return __builtin_bit_cast(u16, (__bf16)f);
}
__device__ inline float bf2f(u16 v) {
  return (float)__builtin_bit_cast(__bf16, v);
}
// fast tanh via exp2-based __expf; abs err ~1e-6 (passed rounds 1-2)
__device__ inline float fast_tanh(float x) {
  x = fminf(15.f, fmaxf(-15.f, x));
  float e = __expf(2.f * x);
  return (e - 1.f) * __builtin_amdgcn_rcpf(e + 1.f);
}

// ---------------------------------------------------------------- prep kernels
__global__ void zero_flags(unsigned* f) {
  int i = blockIdx.x * 256 + threadIdx.x;
  if (i < 3 * 512 * 32) f[i] = 0;
}

// W [2048][1024] fp32 row-major -> Wt [1024 n][2048 k] bf16
__global__ void transpose_w(const float* __restrict__ W0,
                            const float* __restrict__ W1,
                            u16* __restrict__ wt_base) {
  __shared__ float tile[64][65];
  int bi  = blockIdx.x;
  int mat = bi >> 9;
  int t   = bi & 511;
  int tk = t & 31, tn = t >> 5;
  const float* W = mat ? W1 : W0;
  u16* Wt = wt_base + (size_t)mat * 1024 * 2048;
  int K0 = tk * 64, N0 = tn * 64;
  int tid = threadIdx.x;
  {
    int c4 = (tid & 15) * 4;
    int r  = tid >> 4;
    for (int i = 0; i < 4; ++i) {
      int kl = r + i * 16;
      float4 v = *(const float4*)(W + (size_t)(K0 + kl) * 1024 + N0 + c4);
      tile[kl][c4 + 0] = v.x; tile[kl][c4 + 1] = v.y;
      tile[kl][c4 + 2] = v.z; tile[kl][c4 + 3] = v.w;
    }
  }
  __syncthreads();
  {
    int nl = tid >> 3;
    int kc = (tid & 7) * 8;
    for (int pass = 0; pass < 2; ++pass) {
      int n = nl + pass * 32;
      u16x8 o;
      #pragma unroll
      for (int z = 0; z < 8; ++z) o[z] = f2bf(tile[kc + z][n]);
      *(u16x8*)(Wt + (size_t)(N0 + n) * 2048 + K0 + kc) = o;
    }
  }
}

// x [B][T][1024] fp32 -> xb [T][B][1024] bf16 (time-major)
__global__ void xconv(const float* __restrict__ x, u16* __restrict__ xb) {
  int bi = blockIdx.x;               // 32768 = B*T
  int b = bi >> 9, t = bi & 511;
  const float* src = x + ((size_t)b * TT + t) * 1024;
  u16* dst = xb + ((size_t)t * BB + b) * 1024;
  int i = threadIdx.x * 4;
  float4 v = *(const float4*)(src + i);
  u16x4 o; o[0] = f2bf(v.x); o[1] = f2bf(v.y); o[2] = f2bf(v.z); o[3] = f2bf(v.w);
  *(u16x4*)(dst + i) = o;
}

// ------------------------------------------------------------------- sync ops
// Relaxed SYSTEM poll: sc0 sc1 load, bypasses stale L1/L2, NO inv instruction.
__device__ inline void poll1(unsigned* p) {
  while (__hip_atomic_load(p, __ATOMIC_RELAXED, __HIP_MEMORY_SCOPE_SYSTEM) == 0u)
    __builtin_amdgcn_s_sleep(1);
}

// ------------------------------------------------------- MFMA inner GEMM core
// C(16rows x 32cols) += A[rows, k=0..1023] * B(LDS slice). COHA: A via sc1.
template<bool COHA>
__device__ inline void mm_core(const u16* Abase, const u16* bp, size_t aoff,
                               int q, int n15, f32x4& acc0, f32x4& acc1) {
  const u16* ap = Abase + aoff;
  #pragma unroll
  for (int ks = 0; ks < 32; ++ks) {
    bf16x8 a;
    if constexpr (COHA) {
      u64 lo = __hip_atomic_load((u64*)(ap + ks * 32),     __ATOMIC_RELAXED, __HIP_MEMORY_SCOPE_SYSTEM);
      u64 hi = __hip_atomic_load((u64*)(ap + ks * 32 + 4), __ATOMIC_RELAXED, __HIP_MEMORY_SCOPE_SYSTEM);
      union { u64 q2[2]; bf16x8 v; } un; un.q2[0] = lo; un.q2[1] = hi;
      a = un.v;
    } else {
      a = __builtin_bit_cast(bf16x8, *(const u16x8*)(ap + ks * 32));
    }
    int g = (4 * ks + q) ^ n15;          // XOR-16B swizzled group
    bf16x8 b0 = __builtin_bit_cast(bf16x8, *(const u16x8*)(bp + g * 8));
    bf16x8 b1 = __builtin_bit_cast(bf16x8, *(const u16x8*)(bp + 16 * 1024 + g * 8));
    acc0 = __builtin_amdgcn_mfma_f32_16x16x32_bf16(a, b0, acc0, 0, 0, 0);
    acc1 = __builtin_amdgcn_mfma_f32_16x16x32_bf16(a, b1, acc1, 0, 0, 0);
  }
}
// A from fp32 global with inline cvt (only for tiny-ws fallback)
__device__ inline void mmf_core(const float* Ap, const u16* bp,
                                int q, int n15, f32x4& acc0, f32x4& acc1) {
  #pragma unroll
  for (int ks = 0; ks < 32; ++ks) {
    float4 v0 = *(const float4*)(Ap + ks * 32);
    float4 v1 = *(const float4*)(Ap + ks * 32 + 4);
    bf16x8 a;
    a[0]=(__bf16)v0.x; a[1]=(__bf16)v0.y; a[2]=(__bf16)v0.z; a[3]=(__bf16)v0.w;
    a[4]=(__bf16)v1.x; a[5]=(__bf16)v1.y; a[6]=(__bf16)v1.z; a[7]=(__bf16)v1.w;
    int g = (4 * ks + q) ^ n15;
    bf16x8 b0 = __builtin_bit_cast(bf16x8, *(const u16x8*)(bp + g * 8));
    bf16x8 b1 = __builtin_bit_cast(bf16x8, *(const u16x8*)(bp + 16 * 1024 + g * 8));
    acc0 = __builtin_amdgcn_mfma_f32_16x16x32_bf16(a, b0, acc0, 0, 0, 0);
    acc1 = __builtin_amdgcn_mfma_f32_16x16x32_bf16(a, b1, acc1, 0, 0, 0);
  }
}

// ------------------------------------------------------------- main persistent
template<bool COH>   // COH=false: PLAIN no-reuse rings; COH=true: small rings
__global__ void __launch_bounds__(256, 1)
rnn_seq(const float* __restrict__ x, const float* __restrict__ b0v,
        const float* __restrict__ b1v, float* __restrict__ out,
        unsigned* __restrict__ flags, const u16* __restrict__ W0t,
        const u16* __restrict__ W1t, u16* __restrict__ h0r,
        u16* __restrict__ h1r, u16* __restrict__ ur,
        const u16* __restrict__ xb, int use_xb) {
  constexpr int RMASK = COH ? 15 : 511;
  constexpr int UMASK = COH ? 31 : 511;
  constexpr int RING = 16, URING = 32;
  extern __shared__ u16 lds[];     // G1: 2 x (32 cols x 1024 k) = 128 KB
  unsigned* fl_h0 = flags;
  unsigned* fl_h1 = flags + 512 * 32;
  unsigned* fl_u  = flags + 2 * 512 * 32;

  int wg = blockIdx.x, tid = threadIdx.x;
  int grp = wg >> 5, j = wg & 31;        // 0=L0, 1=L1, 2=U
  int n0 = j * 32;
  int lane = tid & 63, wave = tid >> 6;
  int n15 = lane & 15, q = lane >> 4;
  int r0 = wave * 16;

  // ---- persistent LDS weight slice(s), XOR-16B swizzle
  {
    const u16* Wt = (grp == 1) ? W1t : W0t;
    int nh = (grp == 1) ? 2 : 1;
    for (int h = 0; h < nh; ++h) {
      int kb = (grp == 1) ? h * 1024 : (grp == 2 ? 1024 : 0);
      for (int idx = tid; idx < 32 * 128; idx += 256) {
        int n = idx >> 7, g = idx & 127;
        u16x8 v = *(const u16x8*)(Wt + (size_t)(n0 + n) * 2048 + kb + g * 8);
        *(u16x8*)(lds + h * 32768 + n * 1024 + ((g ^ (n & 15)) * 8)) = v;
      }
    }
  }
  __syncthreads();

  const size_t aoff = (size_t)(r0 + n15) * 1024 + q * 8;
  // C/D layout: col = n0 + (lane&15) + 16*tile, row = r0 + q*4 + i
  auto epi = [&](const f32x4& acc0, const f32x4& acc1, auto&& fn) {
    #pragma unroll
    for (int tile = 0; tile < 2; ++tile) {
      const f32x4& a = tile ? acc1 : acc0;
      int nn = n0 + n15 + tile * 16;
      #pragma unroll
      for (int i = 0; i < 4; ++i) fn(r0 + q * 4 + i, nn, a[i]);
    }
  };
  auto sc_store16 = [](u16* p, u16 v) {
    __hip_atomic_store(p, v, __ATOMIC_RELAXED, __HIP_MEMORY_SCOPE_SYSTEM);
  };

  const size_t FIN = (size_t)BB * TT * 1024;

  if (grp == 0) {            // ---- G0: h0(t) = tanh(Wh0*h0(t-1) + U(t))
    for (int t = 0; t < TT; ++t) {
      if (tid < 32)      {                        poll1(&fl_u [t * 32 + tid]); }
      else if (tid < 64) { if (t > 0)             poll1(&fl_h0[(t - 1) * 32 + (tid - 32)]); }
      else if (tid < 96) { if (COH && t >= RING)  poll1(&fl_h1[(t - RING) * 32 + (tid - 64)]); }
      __syncthreads();     // barrier fences stop load hoisting above polls
      f32x4 acc0 = {0.f, 0.f, 0.f, 0.f}, acc1 = acc0;
      if (t > 0)
        mm_core<COH>(h0r + (size_t)((t - 1) & RMASK) * SLOT, lds + n15 * 1024,
                     aoff, q, n15, acc0, acc1);
      u16* Uslab = ur + (size_t)(t & UMASK) * SLOT;
      u16* H = h0r + (size_t)(t & RMASK) * SLOT;
      epi(acc0, acc1, [&](int b, int nn, float a) {
        float uv = COH ? bf2f(__hip_atomic_load(&Uslab[b * 1024 + nn],
                              __ATOMIC_RELAXED, __HIP_MEMORY_SCOPE_SYSTEM))
                       : bf2f(Uslab[b * 1024 + nn]);
        float h = fast_tanh(a + uv);
        sc_store16(&H[b * 1024 + nn], f2bf(h));
        if (t == TT - 1)
          __builtin_nontemporal_store(h, &out[FIN + (size_t)b * 2048 + nn]);
      });
      __syncthreads();     // drains vmcnt(0): all WG stores globally visible
      if (tid == 0)
        __hip_atomic_store(&fl_h0[t * 32 + j], 1u, __ATOMIC_RELAXED, __HIP_MEMORY_SCOPE_SYSTEM);
    }
  } else if (grp == 1) {     // ---- G1: h1(t) = tanh(W1*[h1(t-1); h0(t)] + b1)
    for (int t = 0; t < TT; ++t) {
      // h0(t)-half first (G0 runs ahead; this also hides the h1 wait)
      if (tid < 32) poll1(&fl_h0[t * 32 + tid]);
      __syncthreads();
      f32x4 acc0 = {0.f, 0.f, 0.f, 0.f}, acc1 = acc0;
      mm_core<COH>(h0r + (size_t)(t & RMASK) * SLOT, lds + 32768 + n15 * 1024,
                   aoff, q, n15, acc0, acc1);
      if (t > 0) {
        if (tid < 32) poll1(&fl_h1[(t - 1) * 32 + tid]);
        __syncthreads();
        mm_core<COH>(h1r + (size_t)((t - 1) & RMASK) * SLOT, lds + n15 * 1024,
                     aoff, q, n15, acc0, acc1);
      }
      u16* H = h1r + (size_t)(t & RMASK) * SLOT;
      epi(acc0, acc1, [&](int b, int nn, float a) {
        float h = fast_tanh(a + b1v[nn]);
        sc_store16(&H[b * 1024 + nn], f2bf(h));
        __builtin_nontemporal_store(h, &out[((size_t)b * TT + t) * 1024 + nn]);
        if (t == TT - 1)
          __builtin_nontemporal_store(h, &out[FIN + (size_t)b * 2048 + 1024 + nn]);
      });
      __syncthreads();
      if (tid == 0)
        __hip_atomic_store(&fl_h1[t * 32 + j], 1u, __ATOMIC_RELAXED, __HIP_MEMORY_SCOPE_SYSTEM);
    }
  } else {                   // ---- G2: U(t) = Wx*x(t) + b0 (free-runs)
    for (int t = 0; t < TT; ++t) {
      if (COH && t >= URING) {       // WAR ring gate only when slots reused
        if (tid < 32) poll1(&fl_h0[(t - URING) * 32 + tid]);
        __syncthreads();
      }
      f32x4 acc0 = {0.f, 0.f, 0.f, 0.f}, acc1 = acc0;
      if (use_xb) {  // xb is prep-kernel output: plain cached loads always OK
        mm_core<false>(xb + (size_t)t * SLOT, lds + n15 * 1024,
                       aoff, q, n15, acc0, acc1);
      } else {
        const float* Ap = x + ((size_t)(r0 + n15) * TT + t) * 1024 + q * 8;
        mmf_core(Ap, lds + n15 * 1024, q, n15, acc0, acc1);
      }
      u16* U = ur + (size_t)(t & UMASK) * SLOT;
      epi(acc0, acc1, [&](int b, int nn, float a) {
        sc_store16(&U[b * 1024 + nn], f2bf(a + b0v[nn]));
      });
      __syncthreads();
      if (tid == 0)
        __hip_atomic_store(&fl_u[t * 32 + j], 1u, __ATOMIC_RELAXED, __HIP_MEMORY_SCOPE_SYSTEM);
    }
  }
}

// ------------------------------------------------------------------ host side
extern "C" void kernel_launch(void* const* d_in, const int* in_sizes, int n_in,
                              void* d_out, int out_size, void* d_ws, size_t ws_size,
                              hipStream_t stream) {
  const float* x  = (const float*)d_in[0];
  const float* W0 = (const float*)d_in[1];
  const float* b0 = (const float*)d_in[2];
  const float* W1 = (const float*)d_in[3];
  const float* b1 = (const float*)d_in[4];
  float* out = (float*)d_out;
  unsigned char* ws = (unsigned char*)d_ws;

  // mode select by ws_size
  const size_t WS_PLAIN = OFF_R + 4ull * 512 * SLAB_B;            // ~277 MB
  bool plain = ws_size >= WS_PLAIN;
  size_t nslot  = plain ? 512 : 16;
  size_t nuslot = plain ? 512 : 32;
  size_t o_h0 = OFF_R;
  size_t o_h1 = o_h0 + nslot  * SLAB_B;
  size_t o_u  = o_h1 + nslot  * SLAB_B;
  size_t o_xb = o_u  + nuslot * SLAB_B;
  int use_xb = (plain || ws_size >= o_xb + (size_t)TT * SLAB_B) ? 1 : 0;

  unsigned* flags = (unsigned*)ws;
  const u16* W0t = (const u16*)(ws + OFF_W0T);
  const u16* W1t = (const u16*)(ws + OFF_W1T);
  u16* h0r = (u16*)(ws + o_h0);
  u16* h1r = (u16*)(ws + o_h1);
  u16* ur  = (u16*)(ws + o_u);
  u16* xb  = (u16*)(ws + o_xb);

  zero_flags<<<192, 256, 0, stream>>>(flags);
  transpose_w<<<1024, 256, 0, stream>>>(W0, W1, (u16*)(ws + OFF_W0T));
  if (use_xb) xconv<<<32768, 256, 0, stream>>>(x, xb);

  (void)hipFuncSetAttribute((const void*)rnn_seq<false>,
                            hipFuncAttributeMaxDynamicSharedMemorySize, 131072);
  (void)hipFuncSetAttribute((const void*)rnn_seq<true>,
                            hipFuncAttributeMaxDynamicSharedMemorySize, 131072);

  void* args[12];
  args[0]  = (void*)&x;    args[1]  = (void*)&b0;   args[2]  = (void*)&b1;
  args[3]  = (void*)&out;  args[4]  = (void*)&flags;
  args[5]  = (void*)&W0t;  args[6]  = (void*)&W1t;
  args[7]  = (void*)&h0r;  args[8]  = (void*)&h1r;  args[9]  = (void*)&ur;
  args[10] = (void*)&xb;   args[11] = (void*)&use_xb;
  hipLaunchCooperativeKernel(plain ? (void*)rnn_seq<false> : (void*)rnn_seq<true>,
                             dim3(96), dim3(256), args, 131072, stream);
}

// Round 4
// 4641.762 us; speedup vs baseline: 5.1117x; 1.1610x over previous
//
#include <hip/hip_runtime.h>
#include <cmath>

// ---------------------------------------------------------------------------
// 2-layer tanh RNN, B=64, T=512, D=H0=H1=1024. Persistent cooperative kernel.
// Round-4: attack the cold-read MLP wall. 1024-thr WGs (16 waves/CU), waves =
// 4 row-blocks x 4 K-slices (split-K, LDS fp32 reduce) -> 4x outstanding
// misses per CU on the latency-critical slab reads. Coalesced ring stores via
// LDS bounce (1x4B system store/thread); out-stores moved after the flag.
// Groups (32 WGs each, cols split 32/WG):
//   G0: h0(t) = tanh(Wh0*h0(t-1) + U(t))                [K=1024]
//   G1: h1(t) = tanh(W1*[h1(t-1); h0(t)] + b1)          [K=2048]
//   G2: U(t)  = Wx*x(t) + b0   (free-runs ahead)        [K=1024]
// Sync: relaxed SYSTEM flags/data (write-through, no cache maintenance);
// producer order via __syncthreads' vmcnt(0) drain (verified rounds 2-3).
// ---------------------------------------------------------------------------

typedef unsigned short u16;
typedef unsigned int   u32;
typedef unsigned long long u64;
typedef __bf16 bf16x8 __attribute__((ext_vector_type(8)));
typedef u16    u16x8  __attribute__((ext_vector_type(8)));
typedef u16    u16x4  __attribute__((ext_vector_type(4)));
typedef float  f32x4  __attribute__((ext_vector_type(4)));

constexpr int BB = 64;
constexpr int TT = 512;
constexpr size_t SLOT   = (size_t)64 * 1024;   // elements per [64][1024] slab
constexpr size_t SLAB_B = SLOT * 2;            // 128 KB bf16 slab

constexpr size_t OFF_W0T = 262144;             // flags in [0, 256K)
constexpr size_t OFF_W1T = OFF_W0T + (size_t)1024 * 2048 * 2;
constexpr size_t OFF_R   = OFF_W1T + (size_t)1024 * 2048 * 2;

// LDS budget (dynamic): [weights <=128K][scratch 24K][hcache 4K][ucache 4K]
constexpr int LDS_REQ = 159744;   // G1: 128K + 24K + 4K = 156K  (<=160K/CU)

__device__ inline u16 f2bf(float f) { return __builtin_bit_cast(u16, (__bf16)f); }
__device__ inline float bf2f(u16 v) { return (float)__builtin_bit_cast(__bf16, v); }
__device__ inline float fast_tanh(float x) {
  x = fminf(15.f, fmaxf(-15.f, x));
  float e = __expf(2.f * x);
  return (e - 1.f) * __builtin_amdgcn_rcpf(e + 1.f);
}

// ---------------------------------------------------------------- prep kernels
__global__ void zero_flags(unsigned* f) {
  int i = blockIdx.x * 256 + threadIdx.x;
  if (i < 3 * 512 * 32) f[i] = 0;
}

__global__ void transpose_w(const float* __restrict__ W0,
                            const float* __restrict__ W1,
                            u16* __restrict__ wt_base) {
  __shared__ float tile[64][65];
  int bi  = blockIdx.x;
  int mat = bi >> 9;
  int t   = bi & 511;
  int tk = t & 31, tn = t >> 5;
  const float* W = mat ? W1 : W0;
  u16* Wt = wt_base + (size_t)mat * 1024 * 2048;
  int K0 = tk * 64, N0 = tn * 64;
  int tid = threadIdx.x;
  {
    int c4 = (tid & 15) * 4;
    int r  = tid >> 4;
    for (int i = 0; i < 4; ++i) {
      int kl = r + i * 16;
      float4 v = *(const float4*)(W + (size_t)(K0 + kl) * 1024 + N0 + c4);
      tile[kl][c4 + 0] = v.x; tile[kl][c4 + 1] = v.y;
      tile[kl][c4 + 2] = v.z; tile[kl][c4 + 3] = v.w;
    }
  }
  __syncthreads();
  {
    int nl = tid >> 3;
    int kc = (tid & 7) * 8;
    for (int pass = 0; pass < 2; ++pass) {
      int n = nl + pass * 32;
      u16x8 o;
      #pragma unroll
      for (int z = 0; z < 8; ++z) o[z] = f2bf(tile[kc + z][n]);
      *(u16x8*)(Wt + (size_t)(N0 + n) * 2048 + K0 + kc) = o;
    }
  }
}

__global__ void xconv(const float* __restrict__ x, u16* __restrict__ xb) {
  int bi = blockIdx.x;               // 32768 = B*T
  int b = bi >> 9, t = bi & 511;
  const float* src = x + ((size_t)b * TT + t) * 1024;
  u16* dst = xb + ((size_t)t * BB + b) * 1024;
  int i = threadIdx.x * 4;
  float4 v = *(const float4*)(src + i);
  u16x4 o; o[0] = f2bf(v.x); o[1] = f2bf(v.y); o[2] = f2bf(v.z); o[3] = f2bf(v.w);
  *(u16x4*)(dst + i) = o;
}

// ------------------------------------------------------------------- sync ops
__device__ inline void poll1(unsigned* p) {
  while (__hip_atomic_load(p, __ATOMIC_RELAXED, __HIP_MEMORY_SCOPE_SYSTEM) == 0u)
    __builtin_amdgcn_s_sleep(1);
}

// ------------------------------------------------- per-wave K-slice GEMM core
// This wave: rows r0..r0+15, its 256-wide K slice; 8 ks iters, 2 col tiles.
template<bool COHA>
__device__ inline void mm8(const u16* Abase, const u16* bp, size_t aoff,
                           int gbase, int n15, f32x4& acc0, f32x4& acc1) {
  const u16* ap = Abase + aoff;
  #pragma unroll
  for (int ks = 0; ks < 8; ++ks) {
    bf16x8 a;
    if constexpr (COHA) {
      u64 lo = __hip_atomic_load((u64*)(ap + ks * 32),     __ATOMIC_RELAXED, __HIP_MEMORY_SCOPE_SYSTEM);
      u64 hi = __hip_atomic_load((u64*)(ap + ks * 32 + 4), __ATOMIC_RELAXED, __HIP_MEMORY_SCOPE_SYSTEM);
      union { u64 q2[2]; bf16x8 v; } un; un.q2[0] = lo; un.q2[1] = hi;
      a = un.v;
    } else {
      a = __builtin_bit_cast(bf16x8, *(const u16x8*)(ap + ks * 32));
    }
    int g = (gbase + 4 * ks) ^ n15;          // XOR-16B swizzled group
    bf16x8 b0 = __builtin_bit_cast(bf16x8, *(const u16x8*)(bp + g * 8));
    bf16x8 b1 = __builtin_bit_cast(bf16x8, *(const u16x8*)(bp + 16 * 1024 + g * 8));
    acc0 = __builtin_amdgcn_mfma_f32_16x16x32_bf16(a, b0, acc0, 0, 0, 0);
    acc1 = __builtin_amdgcn_mfma_f32_16x16x32_bf16(a, b1, acc1, 0, 0, 0);
  }
}
// fp32-x fallback (G2, tiny-ws only)
__device__ inline void mmf8(const float* Ap, const u16* bp,
                            int gbase, int n15, f32x4& acc0, f32x4& acc1) {
  #pragma unroll
  for (int ks = 0; ks < 8; ++ks) {
    float4 v0 = *(const float4*)(Ap + ks * 32);
    float4 v1 = *(const float4*)(Ap + ks * 32 + 4);
    bf16x8 a;
    a[0]=(__bf16)v0.x; a[1]=(__bf16)v0.y; a[2]=(__bf16)v0.z; a[3]=(__bf16)v0.w;
    a[4]=(__bf16)v1.x; a[5]=(__bf16)v1.y; a[6]=(__bf16)v1.z; a[7]=(__bf16)v1.w;
    int g = (gbase + 4 * ks) ^ n15;
    bf16x8 b0 = __builtin_bit_cast(bf16x8, *(const u16x8*)(bp + g * 8));
    bf16x8 b1 = __builtin_bit_cast(bf16x8, *(const u16x8*)(bp + 16 * 1024 + g * 8));
    acc0 = __builtin_amdgcn_mfma_f32_16x16x32_bf16(a, b0, acc0, 0, 0, 0);
    acc1 = __builtin_amdgcn_mfma_f32_16x16x32_bf16(a, b1, acc1, 0, 0, 0);
  }
}

// ------------------------------------------------------------- main persistent
template<bool COH>
__global__ void __launch_bounds__(1024, 1)
rnn_seq(const float* __restrict__ x, const float* __restrict__ b0v,
        const float* __restrict__ b1v, float* __restrict__ out,
        unsigned* __restrict__ flags, const u16* __restrict__ W0t,
        const u16* __restrict__ W1t, u16* __restrict__ h0r,
        u16* __restrict__ h1r, u16* __restrict__ ur,
        const u16* __restrict__ xb, int use_xb) {
  constexpr int RMASK = COH ? 15 : 511;
  constexpr int UMASK = COH ? 31 : 511;
  constexpr int RING = 16, URING = 32;
  extern __shared__ u16 lds[];
  unsigned* fl_h0 = flags;
  unsigned* fl_h1 = flags + 512 * 32;
  unsigned* fl_u  = flags + 2 * 512 * 32;

  int wg = blockIdx.x, tid = threadIdx.x;
  int grp = wg >> 5, j = wg & 31;        // 0=L0, 1=L1, 2=U
  int n0 = j * 32;
  int lane = tid & 63, wave = tid >> 6;  // 16 waves
  int rb = wave & 3, ksl = wave >> 2;    // row-block, K-slice
  int n15 = lane & 15, q = lane >> 4;
  int r0 = rb * 16;

  // LDS regions
  u16*   wlds = lds;
  float* scr  = (float*)((char*)lds + ((grp == 1) ? 131072 : 65536));
  u16*   hch  = (u16*)((char*)scr + 24576);
  u32*   uc   = (u32*)((char*)hch + 4096);   // G0 only

  // ---- persistent LDS weights, XOR-16B swizzle, [half][n][k]
  {
    const u16* Wt = (grp == 1) ? W1t : W0t;
    int nh = (grp == 1) ? 2 : 1;
    for (int h = 0; h < nh; ++h) {
      int kb = (grp == 1) ? h * 1024 : (grp == 2 ? 1024 : 0);
      for (int idx = tid; idx < 32 * 128; idx += 1024) {
        int n = idx >> 7, g = idx & 127;
        u16x8 v = *(const u16x8*)(Wt + (size_t)(n0 + n) * 2048 + kb + g * 8);
        *(u16x8*)(wlds + h * 32768 + n * 1024 + ((g ^ (n & 15)) * 8)) = v;
      }
    }
  }
  __syncthreads();

  const size_t aoff = (size_t)(r0 + n15) * 1024 + ksl * 256 + q * 8;
  const int gbase = 32 * ksl + q;
  const u16* bp0 = wlds + n15 * 1024;            // weights half 0
  const u16* bp1 = wlds + 32768 + n15 * 1024;    // weights half 1 (G1)

  // biases hoisted (per-lane constants)
  float bia = 0.f, bib = 0.f;
  if (grp == 1) { bia = b1v[n0 + n15]; bib = b1v[n0 + n15 + 16]; }
  if (grp == 2) { bia = b0v[n0 + n15]; bib = b0v[n0 + n15 + 16]; }

  // split-K reduce helpers ------------------------------------------------
  auto scr_write = [&](const f32x4& a0, const f32x4& a1) {   // waves ksl>0
    int base = ((rb * 3 + ksl - 1) * 2) * 256 + (q * 4) * 16 + n15;
    #pragma unroll
    for (int i = 0; i < 4; ++i) scr[base + i * 16] = a0[i];
    #pragma unroll
    for (int i = 0; i < 4; ++i) scr[base + 256 + i * 16] = a1[i];
  };
  auto scr_sum = [&](f32x4& a0, f32x4& a1) {                 // waves ksl==0
    #pragma unroll
    for (int s = 0; s < 3; ++s) {
      int base = ((rb * 3 + s) * 2) * 256 + (q * 4) * 16 + n15;
      #pragma unroll
      for (int i = 0; i < 4; ++i) a0[i] += scr[base + i * 16];
      #pragma unroll
      for (int i = 0; i < 4; ++i) a1[i] += scr[base + 256 + i * 16];
    }
  };
  // hcache: result as u16 [b 0..63][c 0..31]
  auto hch_write = [&](const f32x4& a0, const f32x4& a1, auto&& act) {
    #pragma unroll
    for (int i = 0; i < 4; ++i) {
      int b = r0 + q * 4 + i;
      hch[b * 32 + n15]      = f2bf(act(a0[i], 0));
      hch[b * 32 + n15 + 16] = f2bf(act(a1[i], 1));
    }
  };
  // coalesced ring store: thread -> 4 B
  const int sb  = tid >> 4;              // 0..63 (batch row)
  const int scc = (tid & 15) * 2;        // col pair
  auto ring_store = [&](u16* slab) {
    u32 v = ((u32*)hch)[tid];
    __hip_atomic_store((u32*)(slab + sb * 1024 + n0 + scc), v,
                       __ATOMIC_RELAXED, __HIP_MEMORY_SCOPE_SYSTEM);
  };

  const size_t FIN = (size_t)BB * TT * 1024;

  if (grp == 0) {            // ---- G0: h0(t) = tanh(Wh0*h0(t-1) + U(t))
    for (int t = 0; t < TT; ++t) {
      if (tid < 32)      { if (t > 0)            poll1(&fl_h0[(t - 1) * 32 + tid]); }
      else if (tid < 64) {                       poll1(&fl_u [t * 32 + (tid - 32)]); }
      else if (tid < 96) { if (COH && t >= RING) poll1(&fl_h1[(t - RING) * 32 + (tid - 64)]); }
      __syncthreads();                                   // B1
      f32x4 acc0 = {0.f, 0.f, 0.f, 0.f}, acc1 = acc0;
      if (t > 0)
        mm8<COH>(h0r + (size_t)((t - 1) & RMASK) * SLOT, bp0, aoff, gbase, n15, acc0, acc1);
      {  // ucache fill: one coalesced 4-B load per thread (U slot t, ready early)
        const u16* us = ur + (size_t)(t & UMASK) * SLOT;
        const u32* up = (const u32*)(us + sb * 1024 + n0 + scc);
        u32 v = COH ? __hip_atomic_load((u32*)up, __ATOMIC_RELAXED, __HIP_MEMORY_SCOPE_SYSTEM)
                    : *up;
        uc[tid] = v;
      }
      if (ksl > 0) scr_write(acc0, acc1);
      __syncthreads();                                   // B2
      if (ksl == 0) {
        scr_sum(acc0, acc1);
        hch_write(acc0, acc1, [&](float a, int tile) {
          int b = 0; (void)b;
          return a;   // placeholder, replaced below
        });
        // redo with U add (need per-element U): inline here
        #pragma unroll
        for (int i = 0; i < 4; ++i) {
          int b = r0 + q * 4 + i;
          float u0 = bf2f(((u16*)uc)[b * 32 + n15]);
          float u1 = bf2f(((u16*)uc)[b * 32 + n15 + 16]);
          hch[b * 32 + n15]      = f2bf(fast_tanh(acc0[i] + u0));
          hch[b * 32 + n15 + 16] = f2bf(fast_tanh(acc1[i] + u1));
        }
      }
      __syncthreads();                                   // B3
      ring_store(h0r + (size_t)(t & RMASK) * SLOT);
      __syncthreads();                                   // B4: vmcnt(0) drain
      if (tid == 0)
        __hip_atomic_store(&fl_h0[t * 32 + j], 1u, __ATOMIC_RELAXED, __HIP_MEMORY_SCOPE_SYSTEM);
      if (t == TT - 1) {   // final state (non-critical, after flag)
        u32 v = ((u32*)hch)[tid];
        float2 o; o.x = bf2f((u16)(v & 0xffff)); o.y = bf2f((u16)(v >> 16));
        *(float2*)&out[FIN + (size_t)sb * 2048 + n0 + scc] = o;
      }
    }
  } else if (grp == 1) {     // ---- G1: h1(t) = tanh(W1*[h1(t-1); h0(t)] + b1)
    for (int t = 0; t < TT; ++t) {
      if (tid < 32) poll1(&fl_h0[t * 32 + tid]);
      __syncthreads();                                   // B1
      f32x4 acc0 = {0.f, 0.f, 0.f, 0.f}, acc1 = acc0;
      mm8<COH>(h0r + (size_t)(t & RMASK) * SLOT, bp1, aoff, gbase, n15, acc0, acc1);
      if (tid < 32 && t > 0) poll1(&fl_h1[(t - 1) * 32 + tid]);
      __syncthreads();                                   // B1b
      if (t > 0)
        mm8<COH>(h1r + (size_t)((t - 1) & RMASK) * SLOT, bp0, aoff, gbase, n15, acc0, acc1);
      if (ksl > 0) scr_write(acc0, acc1);
      __syncthreads();                                   // B2
      if (ksl == 0) {
        scr_sum(acc0, acc1);
        #pragma unroll
        for (int i = 0; i < 4; ++i) {
          int b = r0 + q * 4 + i;
          hch[b * 32 + n15]      = f2bf(fast_tanh(acc0[i] + bia));
          hch[b * 32 + n15 + 16] = f2bf(fast_tanh(acc1[i] + bib));
        }
      }
      __syncthreads();                                   // B3
      ring_store(h1r + (size_t)(t & RMASK) * SLOT);
      __syncthreads();                                   // B4
      if (tid == 0)
        __hip_atomic_store(&fl_h1[t * 32 + j], 1u, __ATOMIC_RELAXED, __HIP_MEMORY_SCOPE_SYSTEM);
      {  // out stores AFTER flag (off the critical drain), coalesced 8 B
        u32 v = ((u32*)hch)[tid];
        float2 o; o.x = bf2f((u16)(v & 0xffff)); o.y = bf2f((u16)(v >> 16));
        __builtin_nontemporal_store(o.x, &out[((size_t)sb * TT + t) * 1024 + n0 + scc]);
        __builtin_nontemporal_store(o.y, &out[((size_t)sb * TT + t) * 1024 + n0 + scc + 1]);
        if (t == TT - 1)
          *(float2*)&out[FIN + (size_t)sb * 2048 + 1024 + n0 + scc] = o;
      }
    }
  } else {                   // ---- G2: U(t) = Wx*x(t) + b0 (free-runs)
    for (int t = 0; t < TT; ++t) {
      if (COH && t >= URING) {
        if (tid < 32) poll1(&fl_h0[(t - URING) * 32 + tid]);
      }
      __syncthreads();                                   // B1
      f32x4 acc0 = {0.f, 0.f, 0.f, 0.f}, acc1 = acc0;
      if (use_xb) {
        mm8<false>(xb + (size_t)t * SLOT, bp0, aoff, gbase, n15, acc0, acc1);
      } else {
        const float* Ap = x + ((size_t)(r0 + n15) * TT + t) * 1024 + ksl * 256 + q * 8;
        mmf8(Ap, bp0, gbase, n15, acc0, acc1);
      }
      if (ksl > 0) scr_write(acc0, acc1);
      __syncthreads();                                   // B2
      if (ksl == 0) {
        scr_sum(acc0, acc1);
        #pragma unroll
        for (int i = 0; i < 4; ++i) {
          int b = r0 + q * 4 + i;
          hch[b * 32 + n15]      = f2bf(acc0[i] + bia);
          hch[b * 32 + n15 + 16] = f2bf(acc1[i] + bib);
        }
      }
      __syncthreads();                                   // B3
      ring_store(ur + (size_t)(t & UMASK) * SLOT);
      __syncthreads();                                   // B4
      if (tid == 0)
        __hip_atomic_store(&fl_u[t * 32 + j], 1u, __ATOMIC_RELAXED, __HIP_MEMORY_SCOPE_SYSTEM);
    }
  }
}

// ------------------------------------------------------------------ host side
extern "C" void kernel_launch(void* const* d_in, const int* in_sizes, int n_in,
                              void* d_out, int out_size, void* d_ws, size_t ws_size,
                              hipStream_t stream) {
  const float* x  = (const float*)d_in[0];
  const float* W0 = (const float*)d_in[1];
  const float* b0 = (const float*)d_in[2];
  const float* W1 = (const float*)d_in[3];
  const float* b1 = (const float*)d_in[4];
  float* out = (float*)d_out;
  unsigned char* ws = (unsigned char*)d_ws;

  const size_t WS_PLAIN = OFF_R + 4ull * 512 * SLAB_B;            // ~277 MB
  bool plain = ws_size >= WS_PLAIN;
  size_t nslot  = plain ? 512 : 16;
  size_t nuslot = plain ? 512 : 32;
  size_t o_h0 = OFF_R;
  size_t o_h1 = o_h0 + nslot  * SLAB_B;
  size_t o_u  = o_h1 + nslot  * SLAB_B;
  size_t o_xb = o_u  + nuslot * SLAB_B;
  int use_xb = (plain || ws_size >= o_xb + (size_t)TT * SLAB_B) ? 1 : 0;

  unsigned* flags = (unsigned*)ws;
  const u16* W0t = (const u16*)(ws + OFF_W0T);
  const u16* W1t = (const u16*)(ws + OFF_W1T);
  u16* h0r = (u16*)(ws + o_h0);
  u16* h1r = (u16*)(ws + o_h1);
  u16* ur  = (u16*)(ws + o_u);
  u16* xb  = (u16*)(ws + o_xb);

  zero_flags<<<192, 256, 0, stream>>>(flags);
  transpose_w<<<1024, 256, 0, stream>>>(W0, W1, (u16*)(ws + OFF_W0T));
  if (use_xb) xconv<<<32768, 256, 0, stream>>>(x, xb);

  (void)hipFuncSetAttribute((const void*)rnn_seq<false>,
                            hipFuncAttributeMaxDynamicSharedMemorySize, LDS_REQ);
  (void)hipFuncSetAttribute((const void*)rnn_seq<true>,
                            hipFuncAttributeMaxDynamicSharedMemorySize, LDS_REQ);

  void* args[12];
  args[0]  = (void*)&x;    args[1]  = (void*)&b0;   args[2]  = (void*)&b1;
  args[3]  = (void*)&out;  args[4]  = (void*)&flags;
  args[5]  = (void*)&W0t;  args[6]  = (void*)&W1t;
  args[7]  = (void*)&h0r;  args[8]  = (void*)&h1r;  args[9]  = (void*)&ur;
  args[10] = (void*)&xb;   args[11] = (void*)&use_xb;
  hipLaunchCooperativeKernel(plain ? (void*)rnn_seq<false> : (void*)rnn_seq<true>,
                             dim3(96), dim3(1024), args, LDS_REQ, stream);
}